// Round 8
// baseline (260.707 us; speedup 1.0000x reference)
//
#include <hip/hip_runtime.h>

#define DM   1024
#define HN   16
#define DKH  64
#define SEQ  2048
#define BATCH 2

typedef __attribute__((ext_vector_type(8))) __bf16 bf16x8;
typedef __attribute__((ext_vector_type(4))) float  f32x4;

#define AS1 __attribute__((address_space(1)))
#define AS3 __attribute__((address_space(3)))
#define GLL(g, l) __builtin_amdgcn_global_load_lds((const AS1 unsigned int*)(const void*)(g), \
                                                   (AS3 unsigned int*)(void*)(l), 16, 0, 0)

__device__ __forceinline__ unsigned short f2bf(float f) {
  union { float f; unsigned u; } v; v.f = f;
  unsigned u = v.u;
  u += 0x7FFFu + ((u >> 16) & 1u);   // round-to-nearest-even
  return (unsigned short)(u >> 16);
}

// ------------- prep: all fp32->bf16 conversions + mask bit-pack, 1 dispatch ----
__global__ __launch_bounds__(256) void prep_kernel(
    const float* __restrict__ q, const float* __restrict__ k,
    const float* __restrict__ v,
    const float* __restrict__ Wq, const float* __restrict__ Wk,
    const float* __restrict__ Wv, const float* __restrict__ Wo,
    const int* __restrict__ mask,
    unsigned short* __restrict__ q_bf, unsigned short* __restrict__ k_bf,
    unsigned short* __restrict__ v_bf,
    unsigned short* __restrict__ Wq_bf, unsigned short* __restrict__ Wk_bf,
    unsigned short* __restrict__ Wv_bf, unsigned short* __restrict__ Wo_bf,
    unsigned* __restrict__ pkm) {
  const int bid = blockIdx.x;
  if (bid < 12288) {
    int t = bid >> 12, r = bid & 4095;
    const float* in = (t == 0) ? q : (t == 1) ? k : v;
    unsigned short* out = (t == 0) ? q_bf : (t == 1) ? k_bf : v_bf;
    int i = r * 256 + threadIdx.x;
    float4 f = ((const float4*)in)[i];
    ushort4 o;
    o.x = f2bf(f.x); o.y = f2bf(f.y); o.z = f2bf(f.z); o.w = f2bf(f.w);
    ((ushort4*)out)[i] = o;
  } else if (bid < 16384) {
    int b2 = bid - 12288;
    int t = b2 >> 10, r = b2 & 1023;
    const float* in = (t == 0) ? Wq : (t == 1) ? Wk : (t == 2) ? Wv : Wo;
    unsigned short* out = (t == 0) ? Wq_bf : (t == 1) ? Wk_bf : (t == 2) ? Wv_bf : Wo_bf;
    int i = r * 256 + threadIdx.x;
    float4 f = ((const float4*)in)[i];
    ushort4 o;
    o.x = f2bf(f.x); o.y = f2bf(f.y); o.z = f2bf(f.z); o.w = f2bf(f.w);
    ((ushort4*)out)[i] = o;
  } else {
    int W = (bid - 16384) * 256 + threadIdx.x;
    const int4* base = (const int4*)(mask + (size_t)(W >> 6) * SEQ + (size_t)(W & 63) * 32);
    unsigned bits = 0;
#pragma unroll
    for (int g = 0; g < 8; ++g) {
      int4 m = base[g];
      bits |= (unsigned)(m.x != 0) << (4 * g);
      bits |= (unsigned)(m.y != 0) << (4 * g + 1);
      bits |= (unsigned)(m.z != 0) << (4 * g + 2);
      bits |= (unsigned)(m.w != 0) << (4 * g + 3);
    }
    pkm[W] = bits;
  }
}

// ---- pipelined GEMM core: 128x128 tile, BK=32, 3-stage LDS, raw s_barrier ----
__device__ __forceinline__ void gemm_core_pipe(
    const unsigned short* __restrict__ A,
    const unsigned short* __restrict__ W,
    unsigned short* lds,   // 24576 shorts: stage s at s*8192, B-half at +4096
    f32x4 (&acc)[4][4]) {
  const int tid = threadIdx.x;
  const int wave = tid >> 6, lane = tid & 63;
  const int l15 = lane & 15, quad = lane >> 4;
  const int wr = wave >> 1, wc = wave & 1;

  const int rl = lane >> 2;
  const int cg = (lane & 3) ^ (((rl & 3) + ((rl >> 2) & 3)) & 3);
  const unsigned short* ga = A + (size_t)(wave * 32 + rl) * DM + cg * 8;
  const unsigned short* gb = W + (size_t)(wave * 32 + rl) * DM + cg * 8;
  unsigned short* la = lds + wave * 1024;
  unsigned short* lb = lds + 4096 + wave * 1024;

  const int cfr = (quad ^ (((l15 & 3) + ((l15 >> 2) & 3)) & 3)) * 8;

  auto stage = [&](int ki, int sb) {
    const unsigned short* a = ga + ki * 32;
    const unsigned short* b = gb + ki * 32;
    GLL(a, la + sb);                    GLL(a + (size_t)16 * DM, la + sb + 512);
    GLL(b, lb + sb);                    GLL(b + (size_t)16 * DM, lb + sb + 512);
  };
  auto compute = [&](int sb) {
    const unsigned short* Ab = lds + sb;
    const unsigned short* Bb = lds + sb + 4096;
    bf16x8 af[4], bfr[4];
#pragma unroll
    for (int mt = 0; mt < 4; ++mt)
      af[mt] = *(const bf16x8*)(Ab + (size_t)(wr * 64 + mt * 16 + l15) * 32 + cfr);
#pragma unroll
    for (int nt = 0; nt < 4; ++nt)
      bfr[nt] = *(const bf16x8*)(Bb + (size_t)(wc * 64 + nt * 16 + l15) * 32 + cfr);
#pragma unroll
    for (int mt = 0; mt < 4; ++mt)
#pragma unroll
      for (int nt = 0; nt < 4; ++nt)
        acc[mt][nt] = __builtin_amdgcn_mfma_f32_16x16x32_bf16(af[mt], bfr[nt], acc[mt][nt], 0, 0, 0);
  };

  stage(0, 0);
  stage(1, 8192);
  int sb0 = 0, sb1 = 8192, sb2 = 16384;
#pragma unroll 1
  for (int i = 0; i < DM / 32 - 2; ++i) {
    stage(i + 2, sb2);
    asm volatile("s_waitcnt vmcnt(8)\ns_barrier" ::: "memory");
    compute(sb0);
    asm volatile("s_barrier" ::: "memory");
    int t = sb0; sb0 = sb1; sb1 = sb2; sb2 = t;
  }
  asm volatile("s_waitcnt vmcnt(4)\ns_barrier" ::: "memory");
  compute(sb0);
  asm volatile("s_waitcnt vmcnt(0)\ns_barrier" ::: "memory");
  compute(sb1);
}

// Fused Q/K/V projections: grid (8, 32, 3). z=0: Q pre-scaled by 0.125*log2(e).
__global__ __launch_bounds__(256, 3) void gemm_qkv(
    const unsigned short* __restrict__ Aq, const unsigned short* __restrict__ Ak,
    const unsigned short* __restrict__ Av,
    const unsigned short* __restrict__ Wq, const unsigned short* __restrict__ Wk,
    const unsigned short* __restrict__ Wv,
    const float* __restrict__ bq, const float* __restrict__ bk,
    const float* __restrict__ bv,
    unsigned short* __restrict__ oq, unsigned short* __restrict__ ok,
    unsigned short* __restrict__ ovT) {
  const int z = blockIdx.z;
  const unsigned short* A = (z == 0) ? Aq : (z == 1) ? Ak : Av;
  const unsigned short* W = (z == 0) ? Wq : (z == 1) ? Wk : Wv;
  const float* bias = (z == 0) ? bq : (z == 1) ? bk : bv;

  __shared__ __align__(16) unsigned short lds[24576];

  const int bn = blockIdx.x * 128, bm = blockIdx.y * 128;
  f32x4 acc[4][4] = {};
  gemm_core_pipe(A + (size_t)bm * DM, W + (size_t)bn * DM, lds, acc);

  const int tid = threadIdx.x;
  const int wave = tid >> 6, lane = tid & 63;
  const int l15 = lane & 15, quad = lane >> 4;
  const int wr = wave >> 1, wc = wave & 1;

  if (z != 2) {
    const float qs = (z == 0) ? 0.125f * 1.44269504088896f : 1.0f;
    unsigned short* out = (z == 0) ? oq : ok;
#pragma unroll
    for (int mt = 0; mt < 4; ++mt)
#pragma unroll
      for (int nt = 0; nt < 4; ++nt) {
        int col = bn + wc * 64 + nt * 16 + l15;
        float bb = bias[col];
#pragma unroll
        for (int r = 0; r < 4; ++r) {
          int row = bm + wr * 64 + mt * 16 + quad * 4 + r;
          out[(size_t)row * DM + col] = f2bf((acc[mt][nt][r] + bb) * qs);
        }
      }
  } else {
    unsigned short* LT = lds;
    __syncthreads();
#pragma unroll
    for (int mt = 0; mt < 4; ++mt)
#pragma unroll
      for (int nt = 0; nt < 4; ++nt) {
        int c = wc * 64 + nt * 16 + l15;
        float bb = bias[bn + c];
        int t0 = wr * 64 + mt * 16 + quad * 4;
        ushort4 w4;
        w4.x = f2bf(acc[mt][nt][0] + bb);
        w4.y = f2bf(acc[mt][nt][1] + bb);
        w4.z = f2bf(acc[mt][nt][2] + bb);
        w4.w = f2bf(acc[mt][nt][3] + bb);
        *(ushort4*)(LT + (size_t)c * 136 + t0) = w4;
      }
    __syncthreads();
    const int b = bm >> 11, sbase = bm & (SEQ - 1);
#pragma unroll
    for (int j = 0; j < 8; ++j) {
      int c = wave * 32 + (j >> 1) * 8 + (lane >> 3);
      int tk = (j & 1) * 64 + (lane & 7) * 8;
      bf16x8 vv = *(const bf16x8*)(LT + (size_t)c * 136 + tk);
      int C = bn + c;
      int h = C >> 6, dk = C & 63;
      *(bf16x8*)(ovT + ((size_t)((b * HN + h) * DKH + dk)) * SEQ + sbase + tk) = vv;
    }
  }
}

// Output projection: 64x128 tile, 512 blocks (2/CU), 3-stage pipeline, fp32 out.
// grid (8, 64). Per stage/wave: A 1 GLL (16 rows), B 2 GLL (32 rows) -> vmcnt(6/3/0).
__global__ __launch_bounds__(256, 4) void gemm_wo(
    const unsigned short* __restrict__ A, const unsigned short* __restrict__ W,
    const float* __restrict__ bias, float* __restrict__ out) {
  __shared__ __align__(16) unsigned short lds[18432];  // 3 x (A 2048 + B 4096)

  const int tid = threadIdx.x;
  const int wave = tid >> 6, lane = tid & 63;
  const int l15 = lane & 15, quad = lane >> 4;
  const int wr = wave >> 1, wc = wave & 1;
  const int bn = blockIdx.x * 128, bm = blockIdx.y * 64;

  const unsigned short* Ab = A + (size_t)bm * DM;
  const unsigned short* Wb = W + (size_t)bn * DM;

  const int rl = lane >> 2;
  const int cg = (lane & 3) ^ (((rl & 3) + ((rl >> 2) & 3)) & 3);
  const unsigned short* ga = Ab + (size_t)(wave * 16 + rl) * DM + cg * 8;
  const unsigned short* gb = Wb + (size_t)(wave * 32 + rl) * DM + cg * 8;
  unsigned short* la = lds + wave * 512;          // 16 rows/wave
  unsigned short* lb = lds + 2048 + wave * 1024;  // 32 rows/wave

  const int cfr = (quad ^ (((l15 & 3) + ((l15 >> 2) & 3)) & 3)) * 8;

  f32x4 acc[2][4] = {};

  auto stage = [&](int ki, int sb) {
    GLL(ga + ki * 32, la + sb);
    const unsigned short* b = gb + ki * 32;
    GLL(b, lb + sb);  GLL(b + (size_t)16 * DM, lb + sb + 512);
  };
  auto compute = [&](int sb) {
    const unsigned short* Aa = lds + sb;
    const unsigned short* Bb = lds + sb + 2048;
    bf16x8 af[2], bfr[4];
#pragma unroll
    for (int mt = 0; mt < 2; ++mt)
      af[mt] = *(const bf16x8*)(Aa + (size_t)(wr * 32 + mt * 16 + l15) * 32 + cfr);
#pragma unroll
    for (int nt = 0; nt < 4; ++nt)
      bfr[nt] = *(const bf16x8*)(Bb + (size_t)(wc * 64 + nt * 16 + l15) * 32 + cfr);
#pragma unroll
    for (int mt = 0; mt < 2; ++mt)
#pragma unroll
      for (int nt = 0; nt < 4; ++nt)
        acc[mt][nt] = __builtin_amdgcn_mfma_f32_16x16x32_bf16(af[mt], bfr[nt], acc[mt][nt], 0, 0, 0);
  };

  stage(0, 0);
  stage(1, 6144);
  int sb0 = 0, sb1 = 6144, sb2 = 12288;
#pragma unroll 1
  for (int i = 0; i < DM / 32 - 2; ++i) {
    stage(i + 2, sb2);
    asm volatile("s_waitcnt vmcnt(6)\ns_barrier" ::: "memory");
    compute(sb0);
    asm volatile("s_barrier" ::: "memory");
    int t = sb0; sb0 = sb1; sb1 = sb2; sb2 = t;
  }
  asm volatile("s_waitcnt vmcnt(3)\ns_barrier" ::: "memory");
  compute(sb0);
  asm volatile("s_waitcnt vmcnt(0)\ns_barrier" ::: "memory");
  compute(sb1);

#pragma unroll
  for (int mt = 0; mt < 2; ++mt)
#pragma unroll
    for (int nt = 0; nt < 4; ++nt) {
      int col = bn + wc * 64 + nt * 16 + l15;
      float bb = bias[col];
#pragma unroll
      for (int r = 0; r < 4; ++r) {
        int row = bm + wr * 32 + mt * 16 + quad * 4 + r;
        out[(size_t)row * DM + col] = acc[mt][nt][r] + bb;
      }
    }
}

// ---------------- flash attention: static softmax, mask prefetched pre-barrier ----
__global__ __launch_bounds__(256, 4) void attn_kernel(
    const unsigned short* __restrict__ qp,
    const unsigned short* __restrict__ kp,
    const unsigned short* __restrict__ vpT,
    const unsigned* __restrict__ pk,
    unsigned short* __restrict__ ctx) {
  const int lane = threadIdx.x & 63;
  const int wave = threadIdx.x >> 6;
  const int l15 = lane & 15, quad = lane >> 4;
  const int bh = blockIdx.x;
  const int b = bh >> 4, h = bh & 15;
  const int qrow = blockIdx.y * 64 + wave * 16 + l15;

  __shared__ __align__(16) unsigned short lds[16384];

  const unsigned short* qb = qp + ((size_t)(b * SEQ + qrow)) * DM + h * DKH + quad * 8;
  bf16x8 qf0 = *(const bf16x8*)qb;
  bf16x8 qf1 = *(const bf16x8*)(qb + 32);

  f32x4 o[4] = {};
  f32x4 lacc = {};
  bf16x8 ones;
#pragma unroll
  for (int i = 0; i < 8; ++i) ones[i] = (__bf16)1.0f;

  const int i8 = lane >> 3;
  const int cs = lane & 7;
  const int cg0 = cs ^ i8;
  const int cg1 = cs ^ i8 ^ 4;
  const unsigned short* kg0 = kp + ((size_t)(b * SEQ + wave * 16 + i8)) * DM + h * DKH + cg0 * 8;
  const unsigned short* kg1 = kp + ((size_t)(b * SEQ + wave * 16 + 8 + i8)) * DM + h * DKH + cg1 * 8;
  const unsigned short* vg0 = vpT + ((size_t)(bh * DKH + wave * 16 + i8)) * SEQ + cg0 * 8;
  const unsigned short* vg1 = vpT + ((size_t)(bh * DKH + wave * 16 + 8 + i8)) * SEQ + cg1 * 8;
  unsigned short* lK = lds + wave * 1024;
  unsigned short* lV = lds + 8192 + wave * 1024;

  const int perm = ((l15 >> 2) << 3) | (l15 & 3);
  int kofs[2][2];
#pragma unroll
  for (int s = 0; s < 2; ++s)
#pragma unroll
    for (int u = 0; u < 2; ++u) {
      int r = perm + 4 * u + 32 * s;
      int sw = (r & 7) ^ (((r >> 3) & 1) << 2);
      kofs[s][u] = r * 64 + ((quad ^ sw) * 8);
    }
  int vofs[4];
#pragma unroll
  for (int t = 0; t < 4; ++t) {
    int r = t * 16 + l15;
    int sw = (r & 7) ^ (((r >> 3) & 1) << 2);
    vofs[t] = r * 64 + ((quad ^ sw) * 8);
  }

  const unsigned* mb = pk + (size_t)(b * SEQ + qrow) * (SEQ / 32);

  auto compute_tile = [&](const unsigned short* Kb, const unsigned short* Vb,
                          unsigned w0, unsigned w1) {
    unsigned bx = w0 >> (quad * 8);
    unsigned by = w1 >> (quad * 8);

    f32x4 sc[2][2];
#pragma unroll
    for (int s = 0; s < 2; ++s)
#pragma unroll
      for (int u = 0; u < 2; ++u) {
        bf16x8 k0 = *(const bf16x8*)(Kb + kofs[s][u]);
        bf16x8 k1 = *(const bf16x8*)(Kb + (kofs[s][u] ^ 32));
        f32x4 a = {};
        a = __builtin_amdgcn_mfma_f32_16x16x32_bf16(k0, qf0, a, 0, 0, 0);
        a = __builtin_amdgcn_mfma_f32_16x16x32_bf16(k1, qf1, a, 0, 0, 0);
        sc[s][u] = a;
      }

    float p[2][2][4];
#pragma unroll
    for (int s = 0; s < 2; ++s)
#pragma unroll
      for (int u = 0; u < 2; ++u) {
        unsigned bits = s ? by : bx;
#pragma unroll
        for (int r = 0; r < 4; ++r) {
          float e = __builtin_amdgcn_exp2f(sc[s][u][r]);
          p[s][u][r] = ((bits >> (4 * u + r)) & 1u) ? e : 0.0f;
        }
      }

    bf16x8 pb[2];
#pragma unroll
    for (int s = 0; s < 2; ++s) {
      bf16x8 t;
      t[0] = (__bf16)p[s][0][0]; t[1] = (__bf16)p[s][0][1];
      t[2] = (__bf16)p[s][0][2]; t[3] = (__bf16)p[s][0][3];
      t[4] = (__bf16)p[s][1][0]; t[5] = (__bf16)p[s][1][1];
      t[6] = (__bf16)p[s][1][2]; t[7] = (__bf16)p[s][1][3];
      pb[s] = t;
    }

#pragma unroll
    for (int s = 0; s < 2; ++s) {
      lacc = __builtin_amdgcn_mfma_f32_16x16x32_bf16(ones, pb[s], lacc, 0, 0, 0);
#pragma unroll
      for (int t = 0; t < 4; ++t) {
        bf16x8 vf = *(const bf16x8*)(Vb + (vofs[t] ^ (s ? 32 : 0)));
        o[t] = __builtin_amdgcn_mfma_f32_16x16x32_bf16(vf, pb[s], o[t], 0, 0, 0);
      }
    }
  };

  GLL(kg0, lK);           GLL(kg1, lK + 512);
  GLL(vg0, lV);           GLL(vg1, lV + 512);

#pragma unroll 1
  for (int j0 = 0; j0 < SEQ; j0 += 128) {
    // mask words for both tiles; the barrier's vmcnt drain completes this free
    uint4 mw = *(const uint4*)(mb + (j0 >> 5));
    __syncthreads();
    if (j0 + 64 < SEQ) {
      GLL(kg0 + (size_t)(j0 + 64) * DM, lK + 4096);
      GLL(kg1 + (size_t)(j0 + 64) * DM, lK + 4096 + 512);
      GLL(vg0 + (j0 + 64), lV + 4096);
      GLL(vg1 + (j0 + 64), lV + 4096 + 512);
    }
    compute_tile(lds, lds + 8192, mw.x, mw.y);

    __syncthreads();
    if (j0 + 128 < SEQ) {
      GLL(kg0 + (size_t)(j0 + 128) * DM, lK);
      GLL(kg1 + (size_t)(j0 + 128) * DM, lK + 512);
      GLL(vg0 + (j0 + 128), lV);
      GLL(vg1 + (j0 + 128), lV + 512);
    }
    compute_tile(lds + 4096, lds + 12288, mw.z, mw.w);
  }

  float inv = 1.0f / lacc[0];
#pragma unroll
  for (int t = 0; t < 4; ++t) {
    ushort4 w;
    w.x = f2bf(o[t][0] * inv);
    w.y = f2bf(o[t][1] * inv);
    w.z = f2bf(o[t][2] * inv);
    w.w = f2bf(o[t][3] * inv);
    *(ushort4*)(ctx + ((size_t)(b * SEQ + qrow)) * DM + h * DKH + t * 16 + quad * 4) = w;
  }
}

// ---------------- launch ----------------
extern "C" void kernel_launch(void* const* d_in, const int* in_sizes, int n_in,
                              void* d_out, int out_size, void* d_ws, size_t ws_size,
                              hipStream_t stream) {
  const float* q    = (const float*)d_in[0];
  const float* k    = (const float*)d_in[1];
  const float* v    = (const float*)d_in[2];
  const int*   mask = (const int*)d_in[3];
  const float* Wq_w = (const float*)d_in[4];
  const float* Wq_b = (const float*)d_in[5];
  const float* Wk_w = (const float*)d_in[6];
  const float* Wk_b = (const float*)d_in[7];
  const float* Wv_w = (const float*)d_in[8];
  const float* Wv_b = (const float*)d_in[9];
  const float* Wo_w = (const float*)d_in[10];
  const float* Wo_b = (const float*)d_in[11];

  char* ws = (char*)d_ws;
  const size_t MB = 1024 * 1024;
  unsigned short* q_bf  = (unsigned short*)(ws + 0 * MB);
  unsigned short* k_bf  = (unsigned short*)(ws + 8 * MB);
  unsigned short* v_bf  = (unsigned short*)(ws + 16 * MB);
  unsigned short* Wq_bf = (unsigned short*)(ws + 24 * MB);
  unsigned short* Wk_bf = (unsigned short*)(ws + 26 * MB);
  unsigned short* Wv_bf = (unsigned short*)(ws + 28 * MB);
  unsigned short* Wo_bf = (unsigned short*)(ws + 30 * MB);
  unsigned short* qp    = (unsigned short*)(ws + 32 * MB);
  unsigned short* kp    = (unsigned short*)(ws + 40 * MB);
  unsigned short* vpT   = (unsigned short*)(ws + 48 * MB);
  unsigned short* ctx   = (unsigned short*)(ws + 56 * MB);
  unsigned* pkm = (unsigned*)d_out;   // consumed by attn before gemm_wo writes d_out

  const int M = BATCH * SEQ;  // 4096

  prep_kernel<<<17408, 256, 0, stream>>>(q, k, v, Wq_w, Wk_w, Wv_w, Wo_w, mask,
                                         q_bf, k_bf, v_bf, Wq_bf, Wk_bf, Wv_bf,
                                         Wo_bf, pkm);

  gemm_qkv<<<dim3(DM / 128, M / 128, 3), 256, 0, stream>>>(
      q_bf, k_bf, v_bf, Wq_bf, Wk_bf, Wv_bf, Wq_b, Wk_b, Wv_b, qp, kp, vpT);

  attn_kernel<<<dim3(BATCH * HN, SEQ / 64), 256, 0, stream>>>(qp, kp, vpT, pkm, ctx);

  gemm_wo<<<dim3(DM / 128, M / 64), 256, 0, stream>>>(ctx, Wo_bf, Wo_b, (float*)d_out);
}